// Round 9
// baseline (260.065 us; speedup 1.0000x reference)
//
#include <hip/hip_runtime.h>

// VQ layer, two-pass certified scheme, BARRIER-FREE main loop.
// score(t,k) = z_t.e_k - 0.5||e_k||^2 ; argmax_k == argmin_k ||z_t-e_k||^2.
//
// Pass 1 (MFMA, bf16x2 3-term, -0.5||e||^2 folded into acc init):
//   eps_hard <= ~3.2e-4; gap >= DELTA=5e-3 certifies winner == fp32 argmin
//   (validated R7/R8). Each wave stages ITS OWN chunk double-buffer via
//   global_load_lds and syncs with s_waitcnt vmcnt(5) only — no
//   __syncthreads in the loop, so waves self-skew and MFMA/LDS/VALU pipes
//   overlap across waves instead of convoying (R8 evidence: barriers made
//   wall ~ sum of pipes).
// Pass 2 (MFMA, bf16x3 6-term == R5 numerics, absmax 0.0 proven): uncertain
//   tokens in 16-token tiles, 4 waves split codebook, 2 independent chains.
//
// d_ws: [0,1.5MB)         emb B-fragments, bf16 3-level, frag-linear
//       [OFF_N,+16KB)     NEGATIVE half-norms: -0.5||e||^2 fp32 per code
//       [OFF_CNT]         u32 uncertain counter (init by pack kernel)
//       [OFF_LIST,+256KB) u32 uncertain-token list
// Fallback to pure-fp32 kernel if ws_size too small.

typedef __attribute__((ext_vector_type(8))) short short8;
typedef __attribute__((ext_vector_type(4))) float f32x4;
typedef unsigned int u32;
typedef __attribute__((address_space(3))) u32 lds_u32;
typedef const __attribute__((address_space(1))) u32 glb_u32;

#define NCHUNK 256                         // 4096 codes / 16 per chunk
#define FRAGS 6                            // 3 levels x 2 K-halves
#define CHUNK_WSB (FRAGS * 64 * 16)        // 6144 B per chunk in ws
#define CHUNK_LDS 4096                     // levels 1-2 only staged in pass 1
#define WSB_BYTES (NCHUNK * CHUNK_WSB)     // 1,572,864
#define OFF_N    WSB_BYTES
#define OFF_CNT  (OFF_N + 16384)
#define OFF_LIST (OFF_CNT + 64)
#define WS_NEEDED ((size_t)OFF_LIST + 65536u * 4u)   // ~1.77 MB
#define DELTA 0.005f

static __device__ __forceinline__ unsigned short f2bf(float f) {
    u32 u = __builtin_bit_cast(u32, f);
    u += 0x7fffu + ((u >> 16) & 1u);       // RNE; inputs finite Gaussians
    return (unsigned short)(u >> 16);
}
static __device__ __forceinline__ float bf2f(unsigned short h) {
    u32 u = ((u32)h) << 16;
    return __builtin_bit_cast(float, u);
}

// ---- prep: pack emb into 3-level bf16 B-fragments + neg-norms + counter --
__global__ void vq_pack_kernel(const float* __restrict__ emb,
                               unsigned short* __restrict__ wsB,
                               float* __restrict__ wsN,
                               u32* __restrict__ wsCnt) {
    int ck    = blockIdx.x;                // 256 blocks x 384 threads
    int f     = threadIdx.x >> 6;
    int lane  = threadIdx.x & 63;
    int level = f >> 1, s = f & 1;
    int code  = ck * 16 + (lane & 15);
    int kb    = s * 32 + (lane >> 4) * 8;
    const float* src = emb + code * 64 + kb;
    short8 o;
#pragma unroll
    for (int j = 0; j < 8; ++j) {
        float x = src[j];
        unsigned short h1 = f2bf(x);
        float r1 = x - bf2f(h1);
        unsigned short h2 = f2bf(r1);
        float r2 = r1 - bf2f(h2);
        unsigned short h3 = f2bf(r2);
        o[j] = (short)(level == 0 ? h1 : (level == 1 ? h2 : h3));
    }
    ((short8*)wsB)[(ck * FRAGS + f) * 64 + lane] = o;

    if (threadIdx.x < 16) {                // exact fp32 NEGATIVE half-norms
        int c = ck * 16 + threadIdx.x;
        const float* e = emb + c * 64;
        float ssum = 0.f;
#pragma unroll
        for (int k = 0; k < 64; ++k) { float v = e[k]; ssum = fmaf(v, v, ssum); }
        wsN[c] = -0.5f * ssum;
    }
    if (ck == 0 && threadIdx.x == 0) *wsCnt = 0u;
}

// ---- pass 1: barrier-free bf16x2 3-term MFMA ----------------------------
// 512 blocks x 512 threads (8 waves). Block owns 128 tokens; wave (h,ws):
// tokens [ws*32,+32) vs codes [h*2048,+2048), private LDS chunk dbuf.
__global__ __launch_bounds__(512, 4) void vq_main_kernel(
    const float* __restrict__ z, const float* __restrict__ emb,
    const unsigned short* __restrict__ wsB, const float* __restrict__ wsN,
    u32* __restrict__ wsCnt, u32* __restrict__ wsList,
    float* __restrict__ out)
{
    __shared__ __align__(16) char sB[8][2][CHUNK_LDS];   // 64 KB, per-wave dbuf

    const int wave = threadIdx.x >> 6;     // 0..7
    const int lane = threadIdx.x & 63;
    const int quad = lane >> 4;
    const int col  = lane & 15;
    const int half = wave >> 2;
    const int wsub = wave & 3;

    // A fragments, bf16 2-level: a[tile][level][khalf], k = kh*32+quad*8+j
    const int t0 = blockIdx.x * 128 + wsub * 32;
    short8 a[2][2][2];
#pragma unroll
    for (int t = 0; t < 2; ++t) {
        const int tok = t0 + t * 16 + col;
        const int b   = tok >> 12;
        const int hw  = tok & 4095;
        const float* zp = z + b * 262144 + hw;
#pragma unroll
        for (int s = 0; s < 2; ++s)
#pragma unroll
            for (int j = 0; j < 8; ++j) {
                int k = s * 32 + quad * 8 + j;
                float x = zp[k * 4096];    // coalesced over col lanes
                unsigned short h1 = f2bf(x);
                a[t][0][s][j] = (short)h1;
                a[t][1][s][j] = (short)f2bf(x - bf2f(h1));
            }
    }

    float best[2][4], best2[2][4];
    int   bidx[2][4];
#pragma unroll
    for (int t = 0; t < 2; ++t)
#pragma unroll
        for (int r = 0; r < 4; ++r) {
            best[t][r] = -3.4e38f; best2[t][r] = -3.4e38f; bidx[t][r] = 0;
        }

    char* myB = &sB[wave][0][0];
    // stage one 4 KB chunk (levels 1-2) into this wave's buffer `buf`
    auto stage = [&](int buf, int ckl) {   // ckl in [0,128)
        const char* gbase = (const char*)wsB + (size_t)(half * 128 + ckl) * CHUNK_WSB;
        char* lbase = myB + buf * CHUNK_LDS;
#pragma unroll
        for (int i = 0; i < 4; ++i)
            __builtin_amdgcn_global_load_lds(
                (glb_u32*)(gbase + i * 1024 + lane * 16),
                (lds_u32*)(lbase + i * 1024), 16, 0, 0);
    };

    stage(0, 0);
    float nrmCur = wsN[(half * 128 + 0) * 16 + col];   // -0.5||e||^2

    for (int i = 0; i < 128; ++i) {
        const int cur = i & 1;
        const int nxt = (i + 1) & 127;     // wrap: last prefetch is benign
        stage(cur ^ 1, nxt);
        float nrmNxt = wsN[(half * 128 + nxt) * 16 + col];

        // own staging for chunk i complete (4 stage + 1 norm newer allowed);
        // "memory" clobber fences compiler reordering of the ds_reads below.
        __asm__ __volatile__("s_waitcnt vmcnt(5)" ::: "memory");

        const char* base = myB + cur * CHUNK_LDS;
        short8 b10 = ((const short8*)(base + 0 * 1024))[lane]; // g1 kh0
        short8 b11 = ((const short8*)(base + 1 * 1024))[lane]; // g1 kh1
        short8 b20 = ((const short8*)(base + 2 * 1024))[lane]; // g2 kh0
        short8 b21 = ((const short8*)(base + 3 * 1024))[lane]; // g2 kh1
        const int code = (half * 128 + i) * 16 + col;

#pragma unroll
        for (int t = 0; t < 2; ++t) {
            f32x4 acc = {nrmCur, nrmCur, nrmCur, nrmCur};
            acc = __builtin_amdgcn_mfma_f32_16x16x32_bf16(a[t][1][0], b10, acc, 0, 0, 0);
            acc = __builtin_amdgcn_mfma_f32_16x16x32_bf16(a[t][1][1], b11, acc, 0, 0, 0);
            acc = __builtin_amdgcn_mfma_f32_16x16x32_bf16(a[t][0][0], b20, acc, 0, 0, 0);
            acc = __builtin_amdgcn_mfma_f32_16x16x32_bf16(a[t][0][1], b21, acc, 0, 0, 0);
            acc = __builtin_amdgcn_mfma_f32_16x16x32_bf16(a[t][0][0], b10, acc, 0, 0, 0);
            acc = __builtin_amdgcn_mfma_f32_16x16x32_bf16(a[t][0][1], b11, acc, 0, 0, 0);

#pragma unroll
            for (int r = 0; r < 4; ++r) {
                float sc = acc[r];
                best2[t][r] = fmaxf(best2[t][r], fminf(sc, best[t][r]));
                bool gt = sc > best[t][r];
                bidx[t][r] = gt ? code : bidx[t][r];
                best[t][r] = fmaxf(best[t][r], sc);
            }
        }
        nrmCur = nrmNxt;
    }

    // drain dangling wrapped prefetch before aliasing sB with merge arrays
    __asm__ __volatile__("s_waitcnt vmcnt(0)" ::: "memory");
    __syncthreads();                       // all waves done with their sB

    // top-2 merge across the 16 cols of each quad group
#pragma unroll
    for (int off = 1; off < 16; off <<= 1)
#pragma unroll
        for (int t = 0; t < 2; ++t)
#pragma unroll
            for (int r = 0; r < 4; ++r) {
                float os1 = __shfl_xor(best[t][r],  off, 64);
                int   oi1 = __shfl_xor(bidx[t][r],  off, 64);
                float os2 = __shfl_xor(best2[t][r], off, 64);
                bool take = (os1 > best[t][r]) ||
                            (os1 == best[t][r] && oi1 < bidx[t][r]);
                float ns2 = take ? fmaxf(best[t][r], os2)
                                 : fmaxf(best2[t][r], os1);
                if (take) { best[t][r] = os1; bidx[t][r] = oi1; }
                best2[t][r] = ns2;
            }

    // merge arrays alias the (drained) staging buffers
    float* sS1  = (float*)&sB[0][0][0];        // [2][128]
    float* sS2  = (float*)&sB[0][0][1024];     // [2][128]
    int*   sI1  = (int*)  &sB[0][0][2048];     // [2][128]
    int*   sOut = (int*)  &sB[0][0][3072];     // [128]

    if (col == 0)
#pragma unroll
        for (int t = 0; t < 2; ++t)
#pragma unroll
            for (int r = 0; r < 4; ++r) {
                int tokb = wsub * 32 + t * 16 + quad * 4 + r;
                sS1[half * 128 + tokb] = best[t][r];
                sS2[half * 128 + tokb] = best2[t][r];
                sI1[half * 128 + tokb] = bidx[t][r];
            }
    __syncthreads();

    // combine halves per token; emit uncertain list
    if (threadIdx.x < 128) {
        const int tk = threadIdx.x;
        float b0 = sS1[tk], b1 = sS1[128 + tk];
        int   i0 = sI1[tk], i1 = sI1[128 + tk];
        float q0 = sS2[tk], q1 = sS2[128 + tk];
        bool take1 = b1 > b0;              // tie -> half0 (lower idx)
        float bw = take1 ? b1 : b0;
        float bl = take1 ? b0 : b1;
        float qw = take1 ? q1 : q0;
        sOut[tk] = take1 ? i1 : i0;
        float second = fmaxf(qw, bl);
        if (bw - second < DELTA) {
            u32 slot = atomicAdd(wsCnt, 1u);
            wsList[slot] = (u32)(blockIdx.x * 128 + tk);
        }
    }
    __syncthreads();

    // gather-write: 512 threads = 128 tokens x 4 channel-groups of 16
    const int tk   = threadIdx.x & 127;
    const int coff = (threadIdx.x >> 7) * 16;
    const int gt   = blockIdx.x * 128 + tk;
    const int ob   = gt >> 12, ohw = gt & 4095;
    float* op = out + ob * 262144 + ohw;
    const float4* ep = (const float4*)(emb + sOut[tk] * 64 + coff);
#pragma unroll
    for (int i = 0; i < 4; ++i) {
        float4 v = ep[i];
        op[(coff + 4 * i + 0) * 4096] = v.x;
        op[(coff + 4 * i + 1) * 4096] = v.y;
        op[(coff + 4 * i + 2) * 4096] = v.z;
        op[(coff + 4 * i + 3) * 4096] = v.w;
    }
}

// ---- pass 2: MFMA bf16x3 6-term repair, two independent chains -----------
__global__ __launch_bounds__(256) void vq_fix_kernel(
    const float* __restrict__ z, const float* __restrict__ emb,
    const unsigned short* __restrict__ wsB, const float* __restrict__ wsN,
    const u32* __restrict__ wsCnt, const u32* __restrict__ wsList,
    float* __restrict__ out)
{
    __shared__ float sS[4][16];
    __shared__ int   sI[4][16];
    __shared__ int   sTok[16];

    const int wave = threadIdx.x >> 6;
    const int lane = threadIdx.x & 63;
    const int quad = lane >> 4;
    const int col  = lane & 15;
    const u32 count = *wsCnt;
    const u32 tiles = (count + 15u) >> 4;

    for (u32 T = blockIdx.x; T < tiles; T += gridDim.x) {
        if (threadIdx.x < 16) {
            u32 slot = T * 16 + threadIdx.x;
            if (slot >= count) slot = count - 1;     // duplicates benign
            sTok[threadIdx.x] = (int)wsList[slot];
        }
        __syncthreads();

        const int tok = sTok[col];
        const int b   = tok >> 12;
        const int hw  = tok & 4095;
        const float* zp = z + b * 262144 + hw;
        short8 a[3][2];
#pragma unroll
        for (int s = 0; s < 2; ++s)
#pragma unroll
            for (int j = 0; j < 8; ++j) {
                int k = s * 32 + quad * 8 + j;
                float x = zp[k * 4096];
                unsigned short h1 = f2bf(x);
                float r1 = x - bf2f(h1);
                unsigned short h2 = f2bf(r1);
                float r2 = r1 - bf2f(h2);
                a[0][s][j] = (short)h1;
                a[1][s][j] = (short)h2;
                a[2][s][j] = (short)f2bf(r2);
            }

        float best[4] = {-3.4e38f, -3.4e38f, -3.4e38f, -3.4e38f};
        int   bidx[4] = {0, 0, 0, 0};

        const short8* Bg = (const short8*)wsB;
        for (int ck = wave * 64; ck < wave * 64 + 64; ++ck) {
            const int fb = ck * FRAGS * 64;
            short8 b10 = Bg[fb + 0 * 64 + lane];
            short8 b11 = Bg[fb + 1 * 64 + lane];
            short8 b20 = Bg[fb + 2 * 64 + lane];
            short8 b21 = Bg[fb + 3 * 64 + lane];
            short8 b30 = Bg[fb + 4 * 64 + lane];
            short8 b31 = Bg[fb + 5 * 64 + lane];
            const float nnrm = wsN[ck * 16 + col];   // -0.5||e||^2
            const int   code = ck * 16 + col;

            f32x4 accA = {0.f, 0.f, 0.f, 0.f};
            f32x4 accB = {0.f, 0.f, 0.f, 0.f};
            accA = __builtin_amdgcn_mfma_f32_16x16x32_bf16(a[1][0], b20, accA, 0, 0, 0);
            accB = __builtin_amdgcn_mfma_f32_16x16x32_bf16(a[0][0], b20, accB, 0, 0, 0);
            accA = __builtin_amdgcn_mfma_f32_16x16x32_bf16(a[1][1], b21, accA, 0, 0, 0);
            accB = __builtin_amdgcn_mfma_f32_16x16x32_bf16(a[0][1], b21, accB, 0, 0, 0);
            accA = __builtin_amdgcn_mfma_f32_16x16x32_bf16(a[0][0], b30, accA, 0, 0, 0);
            accB = __builtin_amdgcn_mfma_f32_16x16x32_bf16(a[1][0], b10, accB, 0, 0, 0);
            accA = __builtin_amdgcn_mfma_f32_16x16x32_bf16(a[0][1], b31, accA, 0, 0, 0);
            accB = __builtin_amdgcn_mfma_f32_16x16x32_bf16(a[1][1], b11, accB, 0, 0, 0);
            accA = __builtin_amdgcn_mfma_f32_16x16x32_bf16(a[2][0], b10, accA, 0, 0, 0);
            accB = __builtin_amdgcn_mfma_f32_16x16x32_bf16(a[0][0], b10, accB, 0, 0, 0);
            accA = __builtin_amdgcn_mfma_f32_16x16x32_bf16(a[2][1], b11, accA, 0, 0, 0);
            accB = __builtin_amdgcn_mfma_f32_16x16x32_bf16(a[0][1], b11, accB, 0, 0, 0);

#pragma unroll
            for (int r = 0; r < 4; ++r) {
                float score = (accA[r] + accB[r]) + nnrm;
                if (score > best[r]) { best[r] = score; bidx[r] = code; }
            }
        }

#pragma unroll
        for (int off = 1; off < 16; off <<= 1)
#pragma unroll
            for (int r = 0; r < 4; ++r) {
                float os = __shfl_xor(best[r], off, 64);
                int   oi = __shfl_xor(bidx[r], off, 64);
                if (os > best[r] || (os == best[r] && oi < bidx[r])) {
                    best[r] = os; bidx[r] = oi;
                }
            }
        if (col == 0)
#pragma unroll
            for (int r = 0; r < 4; ++r) {
                sS[wave][quad * 4 + r] = best[r];
                sI[wave][quad * 4 + r] = bidx[r];
            }
        __syncthreads();

        if (threadIdx.x < 16) {
            float bs = sS[0][threadIdx.x]; int bi = sI[0][threadIdx.x];
#pragma unroll
            for (int w = 1; w < 4; ++w) {
                float s2 = sS[w][threadIdx.x]; int i2 = sI[w][threadIdx.x];
                if (s2 > bs || (s2 == bs && i2 < bi)) { bs = s2; bi = i2; }
            }
            sI[0][threadIdx.x] = bi;
        }
        __syncthreads();

        {
            const int row = threadIdx.x & 15;
            const int cb  = (threadIdx.x >> 4) * 4;
            const int tk2 = sTok[row];
            const int bb  = tk2 >> 12, hh = tk2 & 4095;
            const float* e = emb + sI[0][row] * 64;
            float* op = out + bb * 262144 + hh;
#pragma unroll
            for (int i = 0; i < 4; ++i)
                op[(cb + i) * 4096] = e[cb + i];
        }
        __syncthreads();
    }
}

// ---- fallback (proven Round-1 kernel; used only if ws is too small) ------
__global__ __launch_bounds__(256) void vq_fp32_kernel(
    const float* __restrict__ z, const float* __restrict__ emb,
    float* __restrict__ out)
{
    __shared__ float se[64 * 64];
    __shared__ float snorm[64];

    const int t  = blockIdx.x * 256 + threadIdx.x;
    const int b  = t >> 12;
    const int hw = t & 4095;
    const float* zt = z + (size_t)b * 262144 + hw;
    float zf[64];
#pragma unroll
    for (int c = 0; c < 64; ++c) zf[c] = zt[(size_t)c * 4096];

    float best = -3.4e38f;
    int   bestIdx = 0;
    for (int k0 = 0; k0 < 4096; k0 += 64) {
        __syncthreads();
        const float4* src = (const float4*)(emb + (size_t)k0 * 64);
        float4*       dst = (float4*)se;
#pragma unroll
        for (int i = 0; i < 4; ++i)
            dst[i * 256 + threadIdx.x] = src[i * 256 + threadIdx.x];
        __syncthreads();
        if (threadIdx.x < 64) {
            float s = 0.f;
#pragma unroll
            for (int c = 0; c < 64; ++c) {
                float v = se[threadIdx.x * 64 + c];
                s = fmaf(v, v, s);
            }
            snorm[threadIdx.x] = 0.5f * s;
        }
        __syncthreads();
#pragma unroll 4
        for (int kk = 0; kk < 64; ++kk) {
            float dot = 0.f;
#pragma unroll
            for (int c = 0; c < 64; ++c)
                dot = fmaf(zf[c], se[kk * 64 + c], dot);
            float score = dot - snorm[kk];
            if (score > best) { best = score; bestIdx = k0 + kk; }
        }
    }
    const float* e  = emb + (size_t)bestIdx * 64;
    float*       ot = out + (size_t)b * 262144 + hw;
#pragma unroll
    for (int c = 0; c < 64; ++c) ot[(size_t)c * 4096] = e[c];
}

extern "C" void kernel_launch(void* const* d_in, const int* in_sizes, int n_in,
                              void* d_out, int out_size, void* d_ws, size_t ws_size,
                              hipStream_t stream) {
    const float* z   = (const float*)d_in[0];
    const float* emb = (const float*)d_in[1];
    float*       out = (float*)d_out;

    if (ws_size < WS_NEEDED) {          // constant per session: graph-safe
        vq_fp32_kernel<<<256, 256, 0, stream>>>(z, emb, out);
        return;
    }

    unsigned short* wsB   = (unsigned short*)d_ws;
    float*          wsN   = (float*)((char*)d_ws + OFF_N);
    u32*            wsCnt = (u32*)((char*)d_ws + OFF_CNT);
    u32*            wsList= (u32*)((char*)d_ws + OFF_LIST);

    vq_pack_kernel<<<256, 384, 0, stream>>>(emb, wsB, wsN, wsCnt);
    vq_main_kernel<<<512, 512, 0, stream>>>(z, emb, wsB, wsN, wsCnt, wsList, out);
    vq_fix_kernel<<<128, 256, 0, stream>>>(z, emb, wsB, wsN, wsCnt, wsList, out);
}

// Round 10
// 212.322 us; speedup vs baseline: 1.2249x; 1.2249x over previous
//
#include <hip/hip_runtime.h>

// VQ layer, two-pass certified scheme; pass-1 streams B from L2 to VGPRs.
// score(t,k) = z_t.e_k - 0.5||e_k||^2 ; argmax_k == argmin_k ||z_t-e_k||^2.
//
// Pass 1 (MFMA, bf16x2 3-term, -0.5||e||^2 folded into acc init):
//   eps_hard <= ~3.2e-4; gap >= DELTA=5e-3 certifies winner == fp32 argmin
//   (validated R7/R8). NO LDS, NO barriers in the loop: B-fragments are
//   global_load_dwordx4'd straight into a register double buffer (codebook
//   is 1.5 MB, L2-resident). R8 showed shared-LDS+barrier convoys (wall ~
//   sum of pipes); R9 showed private-LDS staging quadruples traffic. L2->reg
//   streaming avoids both. Wave owns 64 tokens (4 tiles) x half codebook.
// Pass 2 (MFMA, bf16x3 6-term == R5 numerics, absmax 0.0 proven): uncertain
//   tokens in 16-token tiles, 4 waves split codebook, 2 independent chains.
//
// d_ws: [0,1.5MB)         emb B-fragments, bf16 3-level, frag-linear
//       [OFF_N,+16KB)     NEGATIVE half-norms: -0.5||e||^2 fp32 per code
//       [OFF_CNT]         u32 uncertain counter (init by pack kernel)
//       [OFF_LIST,+256KB) u32 uncertain-token list
// Fallback to pure-fp32 kernel if ws_size too small.

typedef __attribute__((ext_vector_type(8))) short short8;
typedef __attribute__((ext_vector_type(4))) float f32x4;
typedef unsigned int u32;

#define NCHUNK 256                         // 4096 codes / 16 per chunk
#define FRAGS 6                            // 3 levels x 2 K-halves
#define CHUNK_WSB (FRAGS * 64 * 16)        // 6144 B per chunk in ws
#define WSB_BYTES (NCHUNK * CHUNK_WSB)     // 1,572,864
#define OFF_N    WSB_BYTES
#define OFF_CNT  (OFF_N + 16384)
#define OFF_LIST (OFF_CNT + 64)
#define WS_NEEDED ((size_t)OFF_LIST + 65536u * 4u)   // ~1.77 MB
#define DELTA 0.005f

static __device__ __forceinline__ unsigned short f2bf(float f) {
    u32 u = __builtin_bit_cast(u32, f);
    u += 0x7fffu + ((u >> 16) & 1u);       // RNE; inputs finite Gaussians
    return (unsigned short)(u >> 16);
}
static __device__ __forceinline__ float bf2f(unsigned short h) {
    u32 u = ((u32)h) << 16;
    return __builtin_bit_cast(float, u);
}

// ---- prep: pack emb into 3-level bf16 B-fragments + neg-norms + counter --
// 16B-group id = (ck*6 + f)*64 + lane;  f = level*2 + s (s = K-half).
// B-frag (16x16x32): n = lane&15, k = s*32 + (lane>>4)*8 + j.
__global__ void vq_pack_kernel(const float* __restrict__ emb,
                               unsigned short* __restrict__ wsB,
                               float* __restrict__ wsN,
                               u32* __restrict__ wsCnt) {
    int ck    = blockIdx.x;                // 256 blocks x 384 threads
    int f     = threadIdx.x >> 6;
    int lane  = threadIdx.x & 63;
    int level = f >> 1, s = f & 1;
    int code  = ck * 16 + (lane & 15);
    int kb    = s * 32 + (lane >> 4) * 8;
    const float* src = emb + code * 64 + kb;
    short8 o;
#pragma unroll
    for (int j = 0; j < 8; ++j) {
        float x = src[j];
        unsigned short h1 = f2bf(x);
        float r1 = x - bf2f(h1);
        unsigned short h2 = f2bf(r1);
        float r2 = r1 - bf2f(h2);
        unsigned short h3 = f2bf(r2);
        o[j] = (short)(level == 0 ? h1 : (level == 1 ? h2 : h3));
    }
    ((short8*)wsB)[(ck * FRAGS + f) * 64 + lane] = o;

    if (threadIdx.x < 16) {                // exact fp32 NEGATIVE half-norms
        int c = ck * 16 + threadIdx.x;
        const float* e = emb + c * 64;
        float ssum = 0.f;
#pragma unroll
        for (int k = 0; k < 64; ++k) { float v = e[k]; ssum = fmaf(v, v, ssum); }
        wsN[c] = -0.5f * ssum;
    }
    if (ck == 0 && threadIdx.x == 0) *wsCnt = 0u;
}

// ---- pass 1: bf16x2 3-term MFMA, B streamed L2 -> VGPR -------------------
// 512 blocks x 256 threads (4 waves). Block owns 128 tokens.
// Wave w: token-group tg=w>>1 (64 tokens = 4 tiles), half=w&1 (2048 codes).
__global__ __launch_bounds__(256, 2) void vq_main_kernel(
    const float* __restrict__ z, const float* __restrict__ emb,
    const unsigned short* __restrict__ wsB, const float* __restrict__ wsN,
    u32* __restrict__ wsCnt, u32* __restrict__ wsList,
    float* __restrict__ out)
{
    __shared__ float sS1[2][128], sS2[2][128];
    __shared__ int   sI1[2][128];
    __shared__ int   sOut[128];

    const int wave = threadIdx.x >> 6;     // 0..3
    const int lane = threadIdx.x & 63;
    const int quad = lane >> 4;
    const int col  = lane & 15;
    const int tg   = wave >> 1;
    const int half = wave & 1;
    const int cbase = half * 128;          // first chunk of this wave's half

    // A fragments, bf16 2-level: a[tile][level][khalf], k = kh*32+quad*8+j
    const int t0 = blockIdx.x * 128 + tg * 64;
    short8 a[4][2][2];
#pragma unroll
    for (int t = 0; t < 4; ++t) {
        const int tok = t0 + t * 16 + col;
        const int b   = tok >> 12;
        const int hw  = tok & 4095;
        const float* zp = z + b * 262144 + hw;
#pragma unroll
        for (int s = 0; s < 2; ++s)
#pragma unroll
            for (int j = 0; j < 8; ++j) {
                int k = s * 32 + quad * 8 + j;
                float x = zp[k * 4096];    // coalesced over col lanes
                unsigned short h1 = f2bf(x);
                a[t][0][s][j] = (short)h1;
                a[t][1][s][j] = (short)f2bf(x - bf2f(h1));
            }
    }

    float best[4][4], best2[4][4];
    int   bidx[4][4];
#pragma unroll
    for (int t = 0; t < 4; ++t)
#pragma unroll
        for (int r = 0; r < 4; ++r) {
            best[t][r] = -3.4e38f; best2[t][r] = -3.4e38f; bidx[t][r] = 0;
        }

    const short8* Bg = (const short8*)wsB;
    // load the 4 level-1/2 fragments of chunk (cbase+i) into regs
    auto loadB = [&](short8* B, int i) {
        const short8* p = Bg + (size_t)(cbase + i) * (FRAGS * 64) + lane;
        B[0] = p[0 * 64];                  // g1 kh0  (1 KB coalesced each)
        B[1] = p[1 * 64];                  // g1 kh1
        B[2] = p[2 * 64];                  // g2 kh0
        B[3] = p[3 * 64];                  // g2 kh1
    };
    auto ldn = [&](int i) { return wsN[(cbase + i) * 16 + col]; };

    // one compute step: 4 tiles x 6 MFMAs + argmax updates
    auto compute = [&](const short8* B, float nrm, int i) {
        const int code = (cbase + i) * 16 + col;
#pragma unroll
        for (int t = 0; t < 4; ++t) {
            f32x4 acc = {nrm, nrm, nrm, nrm};
            acc = __builtin_amdgcn_mfma_f32_16x16x32_bf16(a[t][1][0], B[0], acc, 0, 0, 0);
            acc = __builtin_amdgcn_mfma_f32_16x16x32_bf16(a[t][1][1], B[1], acc, 0, 0, 0);
            acc = __builtin_amdgcn_mfma_f32_16x16x32_bf16(a[t][0][0], B[2], acc, 0, 0, 0);
            acc = __builtin_amdgcn_mfma_f32_16x16x32_bf16(a[t][0][1], B[3], acc, 0, 0, 0);
            acc = __builtin_amdgcn_mfma_f32_16x16x32_bf16(a[t][0][0], B[0], acc, 0, 0, 0);
            acc = __builtin_amdgcn_mfma_f32_16x16x32_bf16(a[t][0][1], B[1], acc, 0, 0, 0);
#pragma unroll
            for (int r = 0; r < 4; ++r) {
                float sc = acc[r];
                best2[t][r] = fmaxf(best2[t][r], fminf(sc, best[t][r]));
                bool gt = sc > best[t][r];
                bidx[t][r] = gt ? code : bidx[t][r];
                best[t][r] = fmaxf(best[t][r], sc);
            }
        }
    };

    // software pipeline, register double buffer, no LDS, no barriers
    short8 B0[4], B1[4];
    float  n0, n1;
    loadB(B0, 0); n0 = ldn(0);
    for (int i = 0; i < 128; i += 2) {
        loadB(B1, i + 1); n1 = ldn(i + 1);
        compute(B0, n0, i);
        if (i + 2 < 128) { loadB(B0, i + 2); n0 = ldn(i + 2); }
        compute(B1, n1, i + 1);
    }

    // top-2 merge across the 16 cols of each quad group
#pragma unroll
    for (int off = 1; off < 16; off <<= 1)
#pragma unroll
        for (int t = 0; t < 4; ++t)
#pragma unroll
            for (int r = 0; r < 4; ++r) {
                float os1 = __shfl_xor(best[t][r],  off, 64);
                int   oi1 = __shfl_xor(bidx[t][r],  off, 64);
                float os2 = __shfl_xor(best2[t][r], off, 64);
                bool take = (os1 > best[t][r]) ||
                            (os1 == best[t][r] && oi1 < bidx[t][r]);
                float ns2 = take ? fmaxf(best[t][r], os2)
                                 : fmaxf(best2[t][r], os1);
                if (take) { best[t][r] = os1; bidx[t][r] = oi1; }
                best2[t][r] = ns2;
            }
    if (col == 0)
#pragma unroll
        for (int t = 0; t < 4; ++t)
#pragma unroll
            for (int r = 0; r < 4; ++r) {
                int tokb = tg * 64 + t * 16 + quad * 4 + r;
                sS1[half][tokb] = best[t][r];
                sS2[half][tokb] = best2[t][r];
                sI1[half][tokb] = bidx[t][r];
            }
    __syncthreads();

    // combine halves per token; emit uncertain list
    if (threadIdx.x < 128) {
        const int tk = threadIdx.x;
        float b0 = sS1[0][tk], b1 = sS1[1][tk];
        int   i0 = sI1[0][tk], i1 = sI1[1][tk];
        float q0 = sS2[0][tk], q1 = sS2[1][tk];
        bool take1 = b1 > b0;              // tie -> half0 (lower idx)
        float bw = take1 ? b1 : b0;
        float bl = take1 ? b0 : b1;
        float qw = take1 ? q1 : q0;
        sOut[tk] = take1 ? i1 : i0;
        float second = fmaxf(qw, bl);
        if (bw - second < DELTA) {
            u32 slot = atomicAdd(wsCnt, 1u);
            wsList[slot] = (u32)(blockIdx.x * 128 + tk);
        }
    }
    __syncthreads();

    // gather-write: 256 threads = 128 tokens x 2 channel-groups of 32
    const int tk   = threadIdx.x & 127;
    const int coff = (threadIdx.x >> 7) * 32;
    const int gt   = blockIdx.x * 128 + tk;
    const int ob   = gt >> 12, ohw = gt & 4095;
    float* op = out + ob * 262144 + ohw;
    const float4* ep = (const float4*)(emb + sOut[tk] * 64 + coff);
#pragma unroll
    for (int i = 0; i < 8; ++i) {
        float4 v = ep[i];
        op[(coff + 4 * i + 0) * 4096] = v.x;
        op[(coff + 4 * i + 1) * 4096] = v.y;
        op[(coff + 4 * i + 2) * 4096] = v.z;
        op[(coff + 4 * i + 3) * 4096] = v.w;
    }
}

// ---- pass 2: MFMA bf16x3 6-term repair, two independent chains -----------
__global__ __launch_bounds__(256) void vq_fix_kernel(
    const float* __restrict__ z, const float* __restrict__ emb,
    const unsigned short* __restrict__ wsB, const float* __restrict__ wsN,
    const u32* __restrict__ wsCnt, const u32* __restrict__ wsList,
    float* __restrict__ out)
{
    __shared__ float sS[4][16];
    __shared__ int   sI[4][16];
    __shared__ int   sTok[16];

    const int wave = threadIdx.x >> 6;
    const int lane = threadIdx.x & 63;
    const int quad = lane >> 4;
    const int col  = lane & 15;
    const u32 count = *wsCnt;
    const u32 tiles = (count + 15u) >> 4;

    for (u32 T = blockIdx.x; T < tiles; T += gridDim.x) {
        if (threadIdx.x < 16) {
            u32 slot = T * 16 + threadIdx.x;
            if (slot >= count) slot = count - 1;     // duplicates benign
            sTok[threadIdx.x] = (int)wsList[slot];
        }
        __syncthreads();

        const int tok = sTok[col];
        const int b   = tok >> 12;
        const int hw  = tok & 4095;
        const float* zp = z + b * 262144 + hw;
        short8 a[3][2];
#pragma unroll
        for (int s = 0; s < 2; ++s)
#pragma unroll
            for (int j = 0; j < 8; ++j) {
                int k = s * 32 + quad * 8 + j;
                float x = zp[k * 4096];
                unsigned short h1 = f2bf(x);
                float r1 = x - bf2f(h1);
                unsigned short h2 = f2bf(r1);
                float r2 = r1 - bf2f(h2);
                a[0][s][j] = (short)h1;
                a[1][s][j] = (short)h2;
                a[2][s][j] = (short)f2bf(r2);
            }

        float best[4] = {-3.4e38f, -3.4e38f, -3.4e38f, -3.4e38f};
        int   bidx[4] = {0, 0, 0, 0};

        const short8* Bg = (const short8*)wsB;
        for (int ck = wave * 64; ck < wave * 64 + 64; ++ck) {
            const size_t fb = (size_t)ck * (FRAGS * 64);
            short8 b10 = Bg[fb + 0 * 64 + lane];
            short8 b11 = Bg[fb + 1 * 64 + lane];
            short8 b20 = Bg[fb + 2 * 64 + lane];
            short8 b21 = Bg[fb + 3 * 64 + lane];
            short8 b30 = Bg[fb + 4 * 64 + lane];
            short8 b31 = Bg[fb + 5 * 64 + lane];
            const float nnrm = wsN[ck * 16 + col];   // -0.5||e||^2
            const int   code = ck * 16 + col;

            f32x4 accA = {0.f, 0.f, 0.f, 0.f};
            f32x4 accB = {0.f, 0.f, 0.f, 0.f};
            accA = __builtin_amdgcn_mfma_f32_16x16x32_bf16(a[1][0], b20, accA, 0, 0, 0);
            accB = __builtin_amdgcn_mfma_f32_16x16x32_bf16(a[0][0], b20, accB, 0, 0, 0);
            accA = __builtin_amdgcn_mfma_f32_16x16x32_bf16(a[1][1], b21, accA, 0, 0, 0);
            accB = __builtin_amdgcn_mfma_f32_16x16x32_bf16(a[0][1], b21, accB, 0, 0, 0);
            accA = __builtin_amdgcn_mfma_f32_16x16x32_bf16(a[0][0], b30, accA, 0, 0, 0);
            accB = __builtin_amdgcn_mfma_f32_16x16x32_bf16(a[1][0], b10, accB, 0, 0, 0);
            accA = __builtin_amdgcn_mfma_f32_16x16x32_bf16(a[0][1], b31, accA, 0, 0, 0);
            accB = __builtin_amdgcn_mfma_f32_16x16x32_bf16(a[1][1], b11, accB, 0, 0, 0);
            accA = __builtin_amdgcn_mfma_f32_16x16x32_bf16(a[2][0], b10, accA, 0, 0, 0);
            accB = __builtin_amdgcn_mfma_f32_16x16x32_bf16(a[0][0], b10, accB, 0, 0, 0);
            accA = __builtin_amdgcn_mfma_f32_16x16x32_bf16(a[2][1], b11, accA, 0, 0, 0);
            accB = __builtin_amdgcn_mfma_f32_16x16x32_bf16(a[0][1], b11, accB, 0, 0, 0);

#pragma unroll
            for (int r = 0; r < 4; ++r) {
                float score = (accA[r] + accB[r]) + nnrm;
                if (score > best[r]) { best[r] = score; bidx[r] = code; }
            }
        }

#pragma unroll
        for (int off = 1; off < 16; off <<= 1)
#pragma unroll
            for (int r = 0; r < 4; ++r) {
                float os = __shfl_xor(best[r], off, 64);
                int   oi = __shfl_xor(bidx[r], off, 64);
                if (os > best[r] || (os == best[r] && oi < bidx[r])) {
                    best[r] = os; bidx[r] = oi;
                }
            }
        if (col == 0)
#pragma unroll
            for (int r = 0; r < 4; ++r) {
                sS[wave][quad * 4 + r] = best[r];
                sI[wave][quad * 4 + r] = bidx[r];
            }
        __syncthreads();

        if (threadIdx.x < 16) {
            float bs = sS[0][threadIdx.x]; int bi = sI[0][threadIdx.x];
#pragma unroll
            for (int w = 1; w < 4; ++w) {
                float s2 = sS[w][threadIdx.x]; int i2 = sI[w][threadIdx.x];
                if (s2 > bs || (s2 == bs && i2 < bi)) { bs = s2; bi = i2; }
            }
            sI[0][threadIdx.x] = bi;
        }
        __syncthreads();

        {
            const int row = threadIdx.x & 15;
            const int cb  = (threadIdx.x >> 4) * 4;
            const int tk2 = sTok[row];
            const int bb  = tk2 >> 12, hh = tk2 & 4095;
            const float* e = emb + sI[0][row] * 64;
            float* op = out + bb * 262144 + hh;
#pragma unroll
            for (int i = 0; i < 4; ++i)
                op[(cb + i) * 4096] = e[cb + i];
        }
        __syncthreads();
    }
}

// ---- fallback (proven Round-1 kernel; used only if ws is too small) ------
__global__ __launch_bounds__(256) void vq_fp32_kernel(
    const float* __restrict__ z, const float* __restrict__ emb,
    float* __restrict__ out)
{
    __shared__ float se[64 * 64];
    __shared__ float snorm[64];

    const int t  = blockIdx.x * 256 + threadIdx.x;
    const int b  = t >> 12;
    const int hw = t & 4095;
    const float* zt = z + (size_t)b * 262144 + hw;
    float zf[64];
#pragma unroll
    for (int c = 0; c < 64; ++c) zf[c] = zt[(size_t)c * 4096];

    float best = -3.4e38f;
    int   bestIdx = 0;
    for (int k0 = 0; k0 < 4096; k0 += 64) {
        __syncthreads();
        const float4* src = (const float4*)(emb + (size_t)k0 * 64);
        float4*       dst = (float4*)se;
#pragma unroll
        for (int i = 0; i < 4; ++i)
            dst[i * 256 + threadIdx.x] = src[i * 256 + threadIdx.x];
        __syncthreads();
        if (threadIdx.x < 64) {
            float s = 0.f;
#pragma unroll
            for (int c = 0; c < 64; ++c) {
                float v = se[threadIdx.x * 64 + c];
                s = fmaf(v, v, s);
            }
            snorm[threadIdx.x] = 0.5f * s;
        }
        __syncthreads();
#pragma unroll 4
        for (int kk = 0; kk < 64; ++kk) {
            float dot = 0.f;
#pragma unroll
            for (int c = 0; c < 64; ++c)
                dot = fmaf(zf[c], se[kk * 64 + c], dot);
            float score = dot - snorm[kk];
            if (score > best) { best = score; bestIdx = k0 + kk; }
        }
    }
    const float* e  = emb + (size_t)bestIdx * 64;
    float*       ot = out + (size_t)b * 262144 + hw;
#pragma unroll
    for (int c = 0; c < 64; ++c) ot[(size_t)c * 4096] = e[c];
}

extern "C" void kernel_launch(void* const* d_in, const int* in_sizes, int n_in,
                              void* d_out, int out_size, void* d_ws, size_t ws_size,
                              hipStream_t stream) {
    const float* z   = (const float*)d_in[0];
    const float* emb = (const float*)d_in[1];
    float*       out = (float*)d_out;

    if (ws_size < WS_NEEDED) {          // constant per session: graph-safe
        vq_fp32_kernel<<<256, 256, 0, stream>>>(z, emb, out);
        return;
    }

    unsigned short* wsB   = (unsigned short*)d_ws;
    float*          wsN   = (float*)((char*)d_ws + OFF_N);
    u32*            wsCnt = (u32*)((char*)d_ws + OFF_CNT);
    u32*            wsList= (u32*)((char*)d_ws + OFF_LIST);

    vq_pack_kernel<<<256, 384, 0, stream>>>(emb, wsB, wsN, wsCnt);
    vq_main_kernel<<<512, 256, 0, stream>>>(z, emb, wsB, wsN, wsCnt, wsList, out);
    vq_fix_kernel<<<256, 256, 0, stream>>>(z, emb, wsB, wsN, wsCnt, wsList, out);
}

// Round 11
// 189.866 us; speedup vs baseline: 1.3697x; 1.1183x over previous
//
#include <hip/hip_runtime.h>

// VQ layer, certified one-main-kernel scheme; B streamed L2 -> VGPRs.
// score(t,k) = z_t.e_k - 0.5||e_k||^2 ; argmax_k == argmin_k ||z_t-e_k||^2.
//
// Pass 1 (in-kernel, MFMA bf16x2 3-term, -0.5||e||^2 folded into acc init):
//   eps_hard <= ~5e-4 (statistical); gap >= DELTA=5e-3 certifies winner ==
//   true fp32 argmin (validated R7-R10: absmax 0.0 at this DELTA).
//   No LDS / no barriers in the hot loop (R8: barriers convoy pipes; R9:
//   private LDS staging multiplies traffic). Register double-buffer of B.
// Repair tail (same kernel, block-local): uncertain tokens (~0-3 per block)
//   rescored with bf16x3 6-term (R5-proven exact-class numerics) by all 4
//   waves splitting the codebook; corrected rows overwritten after a
//   barrier (vmem drained => write order safe). No 3rd kernel, no global
//   list -- R7/R10 evidence: separate fix kernel cost ~55-70 us of wall.
//
// d_ws: [0,1.5MB)      emb B-fragments, bf16 3-level, frag-linear
//       [OFF_N,+16KB)  NEGATIVE half-norms: -0.5||e||^2 fp32 per code
// Fallback to pure-fp32 kernel if ws_size too small.

typedef __attribute__((ext_vector_type(8))) short short8;
typedef __attribute__((ext_vector_type(4))) float f32x4;
typedef unsigned int u32;

#define NCHUNK 256                         // 4096 codes / 16 per chunk
#define FRAGS 6                            // 3 levels x 2 K-halves
#define CHUNK_WSB (FRAGS * 64 * 16)        // 6144 B per chunk in ws
#define WSB_BYTES (NCHUNK * CHUNK_WSB)     // 1,572,864
#define OFF_N    WSB_BYTES
#define WS_NEEDED ((size_t)OFF_N + 16384u) // ~1.52 MB
#define DELTA 0.005f

static __device__ __forceinline__ unsigned short f2bf(float f) {
    u32 u = __builtin_bit_cast(u32, f);
    u += 0x7fffu + ((u >> 16) & 1u);       // RNE; inputs finite Gaussians
    return (unsigned short)(u >> 16);
}
static __device__ __forceinline__ float bf2f(unsigned short h) {
    u32 u = ((u32)h) << 16;
    return __builtin_bit_cast(float, u);
}

// ---- prep: pack emb into 3-level bf16 B-fragments + neg-norms ------------
// 16B-group id = (ck*6 + f)*64 + lane;  f = level*2 + s (s = K-half).
// B-frag (16x16x32): n = lane&15, k = s*32 + (lane>>4)*8 + j.
__global__ void vq_pack_kernel(const float* __restrict__ emb,
                               unsigned short* __restrict__ wsB,
                               float* __restrict__ wsN) {
    int ck    = blockIdx.x;                // 256 blocks x 384 threads
    int f     = threadIdx.x >> 6;
    int lane  = threadIdx.x & 63;
    int level = f >> 1, s = f & 1;
    int code  = ck * 16 + (lane & 15);
    int kb    = s * 32 + (lane >> 4) * 8;
    const float* src = emb + code * 64 + kb;
    short8 o;
#pragma unroll
    for (int j = 0; j < 8; ++j) {
        float x = src[j];
        unsigned short h1 = f2bf(x);
        float r1 = x - bf2f(h1);
        unsigned short h2 = f2bf(r1);
        float r2 = r1 - bf2f(h2);
        unsigned short h3 = f2bf(r2);
        o[j] = (short)(level == 0 ? h1 : (level == 1 ? h2 : h3));
    }
    ((short8*)wsB)[(ck * FRAGS + f) * 64 + lane] = o;

    if (threadIdx.x < 16) {                // exact fp32 NEGATIVE half-norms
        int c = ck * 16 + threadIdx.x;
        const float* e = emb + c * 64;
        float ssum = 0.f;
#pragma unroll
        for (int k = 0; k < 64; ++k) { float v = e[k]; ssum = fmaf(v, v, ssum); }
        wsN[c] = -0.5f * ssum;
    }
}

// ---- main: pass 1 + block-local certified repair -------------------------
// 512 blocks x 256 threads (4 waves). Block owns 128 tokens.
// Pass 1: wave w: token-group tg=w>>1 (64 tokens), half=w&1 (2048 codes).
// Repair: all 4 waves split 4096 codes for the block's uncertain tokens.
__global__ __launch_bounds__(256, 2) void vq_main_kernel(
    const float* __restrict__ z, const float* __restrict__ emb,
    const unsigned short* __restrict__ wsB, const float* __restrict__ wsN,
    float* __restrict__ out)
{
    __shared__ float sS1[2][128], sS2[2][128];
    __shared__ int   sI1[2][128];
    __shared__ int   sOut[128];
    __shared__ int   sUList[128];
    __shared__ int   sUCnt;
    __shared__ float sRS[4][16];
    __shared__ int   sRI[4][16];

    const int wave = threadIdx.x >> 6;     // 0..3
    const int lane = threadIdx.x & 63;
    const int quad = lane >> 4;
    const int col  = lane & 15;
    const int tg   = wave >> 1;
    const int half = wave & 1;
    const int cbase = half * 128;          // first chunk of this wave's half

    if (threadIdx.x == 0) sUCnt = 0;

    // A fragments, bf16 2-level: a[tile][level][khalf], k = kh*32+quad*8+j
    const int t0 = blockIdx.x * 128 + tg * 64;
    short8 a[4][2][2];
#pragma unroll
    for (int t = 0; t < 4; ++t) {
        const int tok = t0 + t * 16 + col;
        const int b   = tok >> 12;
        const int hw  = tok & 4095;
        const float* zp = z + b * 262144 + hw;
#pragma unroll
        for (int s = 0; s < 2; ++s)
#pragma unroll
            for (int j = 0; j < 8; ++j) {
                int k = s * 32 + quad * 8 + j;
                float x = zp[k * 4096];    // coalesced over col lanes
                unsigned short h1 = f2bf(x);
                a[t][0][s][j] = (short)h1;
                a[t][1][s][j] = (short)f2bf(x - bf2f(h1));
            }
    }

    float best[4][4], best2[4][4];
    int   bidx[4][4];
#pragma unroll
    for (int t = 0; t < 4; ++t)
#pragma unroll
        for (int r = 0; r < 4; ++r) {
            best[t][r] = -3.4e38f; best2[t][r] = -3.4e38f; bidx[t][r] = 0;
        }

    const short8* Bg = (const short8*)wsB;
    auto loadB = [&](short8* B, int i) {   // 4 level-1/2 frags of chunk
        const short8* p = Bg + (size_t)(cbase + i) * (FRAGS * 64) + lane;
        B[0] = p[0 * 64];                  // g1 kh0  (1 KB coalesced each)
        B[1] = p[1 * 64];                  // g1 kh1
        B[2] = p[2 * 64];                  // g2 kh0
        B[3] = p[3 * 64];                  // g2 kh1
    };
    auto ldn = [&](int i) { return wsN[(cbase + i) * 16 + col]; };

    auto compute = [&](const short8* B, float nrm, int i) {
        const int code = (cbase + i) * 16 + col;
#pragma unroll
        for (int t = 0; t < 4; ++t) {
            f32x4 acc = {nrm, nrm, nrm, nrm};
            acc = __builtin_amdgcn_mfma_f32_16x16x32_bf16(a[t][1][0], B[0], acc, 0, 0, 0);
            acc = __builtin_amdgcn_mfma_f32_16x16x32_bf16(a[t][1][1], B[1], acc, 0, 0, 0);
            acc = __builtin_amdgcn_mfma_f32_16x16x32_bf16(a[t][0][0], B[2], acc, 0, 0, 0);
            acc = __builtin_amdgcn_mfma_f32_16x16x32_bf16(a[t][0][1], B[3], acc, 0, 0, 0);
            acc = __builtin_amdgcn_mfma_f32_16x16x32_bf16(a[t][0][0], B[0], acc, 0, 0, 0);
            acc = __builtin_amdgcn_mfma_f32_16x16x32_bf16(a[t][0][1], B[1], acc, 0, 0, 0);
#pragma unroll
            for (int r = 0; r < 4; ++r) {
                float sc = acc[r];
                // med3(new, best, best2) == new second-best (identical math,
                // 1 VALU less than max(best2, min(sc, best)))
                best2[t][r] = __builtin_amdgcn_fmed3f(sc, best[t][r], best2[t][r]);
                bool gt = sc > best[t][r];
                bidx[t][r] = gt ? code : bidx[t][r];
                best[t][r] = fmaxf(best[t][r], sc);
            }
        }
    };

    // software pipeline, register double buffer, no LDS, no barriers
    short8 B0[4], B1[4];
    float  n0, n1;
    loadB(B0, 0); n0 = ldn(0);
    for (int i = 0; i < 128; i += 2) {
        loadB(B1, i + 1); n1 = ldn(i + 1);
        compute(B0, n0, i);
        if (i + 2 < 128) { loadB(B0, i + 2); n0 = ldn(i + 2); }
        compute(B1, n1, i + 1);
    }

    // top-2 merge across the 16 cols of each quad group
#pragma unroll
    for (int off = 1; off < 16; off <<= 1)
#pragma unroll
        for (int t = 0; t < 4; ++t)
#pragma unroll
            for (int r = 0; r < 4; ++r) {
                float os1 = __shfl_xor(best[t][r],  off, 64);
                int   oi1 = __shfl_xor(bidx[t][r],  off, 64);
                float os2 = __shfl_xor(best2[t][r], off, 64);
                bool take = (os1 > best[t][r]) ||
                            (os1 == best[t][r] && oi1 < bidx[t][r]);
                float ns2 = take ? fmaxf(best[t][r], os2)
                                 : fmaxf(best2[t][r], os1);
                if (take) { best[t][r] = os1; bidx[t][r] = oi1; }
                best2[t][r] = ns2;
            }
    if (col == 0)
#pragma unroll
        for (int t = 0; t < 4; ++t)
#pragma unroll
            for (int r = 0; r < 4; ++r) {
                int tokb = tg * 64 + t * 16 + quad * 4 + r;
                sS1[half][tokb] = best[t][r];
                sS2[half][tokb] = best2[t][r];
                sI1[half][tokb] = bidx[t][r];
            }
    __syncthreads();

    // combine halves per token; uncertain -> block-local LDS list
    if (threadIdx.x < 128) {
        const int tk = threadIdx.x;
        float b0 = sS1[0][tk], b1 = sS1[1][tk];
        int   i0 = sI1[0][tk], i1 = sI1[1][tk];
        float q0 = sS2[0][tk], q1 = sS2[1][tk];
        bool take1 = b1 > b0;              // tie -> half0 (lower idx)
        float bw = take1 ? b1 : b0;
        float bl = take1 ? b0 : b1;
        float qw = take1 ? q1 : q0;
        sOut[tk] = take1 ? i1 : i0;
        float second = fmaxf(qw, bl);
        if (bw - second < DELTA) {
            int s = atomicAdd(&sUCnt, 1);  // LDS atomic
            sUList[s] = tk;
        }
    }
    __syncthreads();

    // gather-write for ALL tokens (uncertain ones corrected below; the
    // barrier's vmem drain orders the overwrite after this write)
    {
        const int tk   = threadIdx.x & 127;
        const int coff = (threadIdx.x >> 7) * 32;
        const int gt   = blockIdx.x * 128 + tk;
        const int ob   = gt >> 12, ohw = gt & 4095;
        float* op = out + ob * 262144 + ohw;
        const float4* ep = (const float4*)(emb + sOut[tk] * 64 + coff);
#pragma unroll
        for (int i = 0; i < 8; ++i) {
            float4 v = ep[i];
            op[(coff + 4 * i + 0) * 4096] = v.x;
            op[(coff + 4 * i + 1) * 4096] = v.y;
            op[(coff + 4 * i + 2) * 4096] = v.z;
            op[(coff + 4 * i + 3) * 4096] = v.w;
        }
    }
    __syncthreads();

    // ---- repair tail: bf16x3 6-term exact-class rescore (R5 numerics) ----
    const int cnt = sUCnt;
    for (int T0 = 0; T0 < cnt; T0 += 16) {
        int slot = T0 + col;
        if (slot >= cnt) slot = cnt - 1;   // duplicates benign
        const int tokb = sUList[slot];
        const int gt2  = blockIdx.x * 128 + tokb;
        const int b2   = gt2 >> 12, hw2 = gt2 & 4095;
        const float* zp2 = z + b2 * 262144 + hw2;

        short8 af[3][2];
#pragma unroll
        for (int s = 0; s < 2; ++s)
#pragma unroll
            for (int j = 0; j < 8; ++j) {
                int k = s * 32 + quad * 8 + j;
                float x = zp2[k * 4096];
                unsigned short h1 = f2bf(x);
                float r1 = x - bf2f(h1);
                unsigned short h2 = f2bf(r1);
                float r2 = r1 - bf2f(h2);
                af[0][s][j] = (short)h1;
                af[1][s][j] = (short)h2;
                af[2][s][j] = (short)f2bf(r2);
            }

        float rb[4] = {-3.4e38f, -3.4e38f, -3.4e38f, -3.4e38f};
        int   ri[4] = {0, 0, 0, 0};

        auto ldf = [&](short8* F, int ck) {      // all 6 frags of chunk ck
            const short8* p = Bg + (size_t)ck * (FRAGS * 64) + lane;
#pragma unroll
            for (int q = 0; q < 6; ++q) F[q] = p[q * 64];
        };
        auto rstep = [&](const short8* F, int ck) {
            const float nnrm = wsN[ck * 16 + col];
            const int   code = ck * 16 + col;
            f32x4 accA = {0.f, 0.f, 0.f, 0.f};
            f32x4 accB = {0.f, 0.f, 0.f, 0.f};
            accA = __builtin_amdgcn_mfma_f32_16x16x32_bf16(af[1][0], F[2], accA, 0, 0, 0);
            accB = __builtin_amdgcn_mfma_f32_16x16x32_bf16(af[0][0], F[2], accB, 0, 0, 0);
            accA = __builtin_amdgcn_mfma_f32_16x16x32_bf16(af[1][1], F[3], accA, 0, 0, 0);
            accB = __builtin_amdgcn_mfma_f32_16x16x32_bf16(af[0][1], F[3], accB, 0, 0, 0);
            accA = __builtin_amdgcn_mfma_f32_16x16x32_bf16(af[0][0], F[4], accA, 0, 0, 0);
            accB = __builtin_amdgcn_mfma_f32_16x16x32_bf16(af[1][0], F[0], accB, 0, 0, 0);
            accA = __builtin_amdgcn_mfma_f32_16x16x32_bf16(af[0][1], F[5], accA, 0, 0, 0);
            accB = __builtin_amdgcn_mfma_f32_16x16x32_bf16(af[1][1], F[1], accB, 0, 0, 0);
            accA = __builtin_amdgcn_mfma_f32_16x16x32_bf16(af[2][0], F[0], accA, 0, 0, 0);
            accB = __builtin_amdgcn_mfma_f32_16x16x32_bf16(af[0][0], F[0], accB, 0, 0, 0);
            accA = __builtin_amdgcn_mfma_f32_16x16x32_bf16(af[2][1], F[1], accA, 0, 0, 0);
            accB = __builtin_amdgcn_mfma_f32_16x16x32_bf16(af[0][1], F[1], accB, 0, 0, 0);
#pragma unroll
            for (int r = 0; r < 4; ++r) {
                float score = (accA[r] + accB[r]) + nnrm;
                if (score > rb[r]) { rb[r] = score; ri[r] = code; }
            }
        };

        // wave covers 64 chunks, register-double-buffered
        const int ck0 = wave * 64;
        short8 F0[6], F1[6];
        ldf(F0, ck0);
        for (int i = 0; i < 64; i += 2) {
            ldf(F1, ck0 + i + 1);
            rstep(F0, ck0 + i);
            if (i + 2 < 64) ldf(F0, ck0 + i + 2);
            rstep(F1, ck0 + i + 1);
        }

#pragma unroll
        for (int off = 1; off < 16; off <<= 1)
#pragma unroll
            for (int r = 0; r < 4; ++r) {
                float os = __shfl_xor(rb[r], off, 64);
                int   oi = __shfl_xor(ri[r], off, 64);
                if (os > rb[r] || (os == rb[r] && oi < ri[r])) {
                    rb[r] = os; ri[r] = oi;
                }
            }
        if (col == 0)
#pragma unroll
            for (int r = 0; r < 4; ++r) {
                sRS[wave][quad * 4 + r] = rb[r];
                sRI[wave][quad * 4 + r] = ri[r];
            }
        __syncthreads();

        if (threadIdx.x < 16) {            // waves cover ascending ranges
            float bs = sRS[0][threadIdx.x]; int bi = sRI[0][threadIdx.x];
#pragma unroll
            for (int w = 1; w < 4; ++w) {
                float s2 = sRS[w][threadIdx.x]; int i2 = sRI[w][threadIdx.x];
                if (s2 > bs || (s2 == bs && i2 < bi)) { bs = s2; bi = i2; }
            }
            sRI[0][threadIdx.x] = bi;
        }
        __syncthreads();

        {   // overwrite the repaired tokens' rows (dup rows write same data)
            const int row = threadIdx.x & 15;
            int rslot = T0 + row;
            if (rslot >= cnt) rslot = cnt - 1;
            const int cb  = (threadIdx.x >> 4) * 4;
            const int tk2 = sUList[rslot];
            const int g3  = blockIdx.x * 128 + tk2;
            const int bb  = g3 >> 12, hh = g3 & 4095;
            const float* e = emb + sRI[0][row] * 64;
            float* op = out + bb * 262144 + hh;
#pragma unroll
            for (int i = 0; i < 4; ++i)
                op[(cb + i) * 4096] = e[cb + i];
        }
        __syncthreads();                   // sRS/sRI reuse next tile
    }
}

// ---- fallback (proven Round-1 kernel; used only if ws is too small) ------
__global__ __launch_bounds__(256) void vq_fp32_kernel(
    const float* __restrict__ z, const float* __restrict__ emb,
    float* __restrict__ out)
{
    __shared__ float se[64 * 64];
    __shared__ float snorm[64];

    const int t  = blockIdx.x * 256 + threadIdx.x;
    const int b  = t >> 12;
    const int hw = t & 4095;
    const float* zt = z + (size_t)b * 262144 + hw;
    float zf[64];
#pragma unroll
    for (int c = 0; c < 64; ++c) zf[c] = zt[(size_t)c * 4096];

    float best = -3.4e38f;
    int   bestIdx = 0;
    for (int k0 = 0; k0 < 4096; k0 += 64) {
        __syncthreads();
        const float4* src = (const float4*)(emb + (size_t)k0 * 64);
        float4*       dst = (float4*)se;
#pragma unroll
        for (int i = 0; i < 4; ++i)
            dst[i * 256 + threadIdx.x] = src[i * 256 + threadIdx.x];
        __syncthreads();
        if (threadIdx.x < 64) {
            float s = 0.f;
#pragma unroll
            for (int c = 0; c < 64; ++c) {
                float v = se[threadIdx.x * 64 + c];
                s = fmaf(v, v, s);
            }
            snorm[threadIdx.x] = 0.5f * s;
        }
        __syncthreads();
#pragma unroll 4
        for (int kk = 0; kk < 64; ++kk) {
            float dot = 0.f;
#pragma unroll
            for (int c = 0; c < 64; ++c)
                dot = fmaf(zf[c], se[kk * 64 + c], dot);
            float score = dot - snorm[kk];
            if (score > best) { best = score; bestIdx = k0 + kk; }
        }
    }
    const float* e  = emb + (size_t)bestIdx * 64;
    float*       ot = out + (size_t)b * 262144 + hw;
#pragma unroll
    for (int c = 0; c < 64; ++c) ot[(size_t)c * 4096] = e[c];
}

extern "C" void kernel_launch(void* const* d_in, const int* in_sizes, int n_in,
                              void* d_out, int out_size, void* d_ws, size_t ws_size,
                              hipStream_t stream) {
    const float* z   = (const float*)d_in[0];
    const float* emb = (const float*)d_in[1];
    float*       out = (float*)d_out;

    if (ws_size < WS_NEEDED) {          // constant per session: graph-safe
        vq_fp32_kernel<<<256, 256, 0, stream>>>(z, emb, out);
        return;
    }

    unsigned short* wsB = (unsigned short*)d_ws;
    float*          wsN = (float*)((char*)d_ws + OFF_N);

    vq_pack_kernel<<<256, 384, 0, stream>>>(emb, wsB, wsN);
    vq_main_kernel<<<512, 256, 0, stream>>>(z, emb, wsB, wsN, out);
}